// Round 1
// 697.897 us; speedup vs baseline: 1.4905x; 1.4905x over previous
//
#include <hip/hip_runtime.h>
#include <math.h>

// Cross-attention forward, B=32, LQ=64, LKV=4096, D=512, fp32 in/out.
// Round 5: ALGEBRAIC restructure — eliminate the K/V projections over the
// 131072-key axis entirely:
//   scores: q.k = (q~ Wk).x2^T + (q~.bk)  [row-const -> softmax-invariant]
//           => S = M @ x2^T with M = (x1 Wq^T + bq) Wk   (2048x512, tiny)
//   output: P@(x2 Wv^T + bv) = (P@x2) Wv^T + bv  [sum_k P = 1]
//           => attn computes U = P@x2; final tiny GEMM applies Wv + bv.
// attn/combine structure verified in round 4 reused as-is:
//   M2 -> Q2 slot, x2m (hi|lo) -> K2 slot, x2ht (hi, transposed) -> Vt slot.
// MFMA work drops 3.9e11 -> 5.6e10 FLOPs; K2/Vt HBM round-trips (~800 MB) gone.

#define LQ 64
#define LKV 4096
#define NB 32
#define DM 512
#define SCALE 22.627416997969522f   // sqrt(512)
#define KEYS_TOTAL (NB * LKV)       // 131072
#define NCHUNK 16                   // chunks per batch
#define CHUNK 256                   // keys per attn block
#define PBS 264                     // Pb row stride (ushorts)

typedef __attribute__((ext_vector_type(8))) short bf16x8;
typedef __attribute__((ext_vector_type(4))) float f32x4;
typedef __attribute__((ext_vector_type(8))) unsigned short u16x8;
typedef __attribute__((ext_vector_type(4))) unsigned short u16x4;

__device__ __forceinline__ unsigned short f2bf(float f) {   // RNE fp32->bf16
    unsigned u = __float_as_uint(f);
    u += 0x7fffu + ((u >> 16) & 1u);
    return (unsigned short)(u >> 16);
}
__device__ __forceinline__ float bf2f(unsigned short s) {
    return __uint_as_float(((unsigned)s) << 16);
}
__device__ __forceinline__ void gld16(const void* g, void* l) {
    __builtin_amdgcn_global_load_lds(
        (const __attribute__((address_space(1))) unsigned int*)g,
        (__attribute__((address_space(3))) unsigned int*)l, 16, 0, 0);
}

// ---------------- split: fp32 -> hi/lo bf16, 8 elems/thread -----------------
__global__ __launch_bounds__(256) void split_kernel(const float* __restrict__ src,
                                                    unsigned short* __restrict__ hi,
                                                    unsigned short* __restrict__ lo) {
    size_t idx = ((size_t)blockIdx.x * 256 + threadIdx.x) * 8;
    float4 a = *(const float4*)(src + idx);
    float4 b = *(const float4*)(src + idx + 4);
    float ff[8] = {a.x, a.y, a.z, a.w, b.x, b.y, b.z, b.w};
    u16x8 h, l;
#pragma unroll
    for (int i = 0; i < 8; ++i) {
        h[i] = f2bf(ff[i]);
        l[i] = f2bf(ff[i] - bf2f(h[i]));
    }
    *(u16x8*)(hi + idx) = h;
    *(u16x8*)(lo + idx) = l;
}

// ---------------- fp32 512x512 transpose ------------------------------------
__global__ __launch_bounds__(256) void transpose_kernel(const float* __restrict__ in,
                                                        float* __restrict__ outT) {
    __shared__ float T[64 * 65];
    const int bx = blockIdx.x * 64, by = blockIdx.y * 64;
    const int t = threadIdx.x, col = t & 63, rg = t >> 6;
#pragma unroll
    for (int i = 0; i < 16; ++i) {
        int row = i * 4 + rg;
        T[col * 65 + row] = in[(size_t)(by + row) * DM + bx + col];
    }
    __syncthreads();
#pragma unroll
    for (int i = 0; i < 16; ++i) {
        int row = i * 4 + rg;
        outT[(size_t)(bx + row) * DM + by + col] = T[row * 65 + col];
    }
}

// ---------------- bM[d] = sum_e bq[e] * Wk[e,d] -----------------------------
__global__ __launch_bounds__(256) void bmfold_kernel(const float* __restrict__ bq,
                                                     const float* __restrict__ wk,
                                                     float* __restrict__ bM) {
    int d = blockIdx.x * 256 + threadIdx.x;
    float s = 0.f;
#pragma unroll 8
    for (int e = 0; e < 512; ++e) s = fmaf(bq[e], wk[(size_t)e * DM + d], s);
    bM[d] = s;
}

// ---------------- small 3-term split-precision GEMM -------------------------
// out[row,col] = sum_k A[row,k]*B[col,k] + bias[col], A/B in hi/lo bf16 pairs.
// BM=BN=128, BK=32, 256 thr (4 waves 2x2), 16x16x32 bf16 (clone of the
// round-4 proj K-path core, harness-verified). K = DM = 512 always.
// mode 0: merged hi|lo output [row][1024]  (for M2, attn Q2 format)
// mode 1: fp32 output [row][512]           (final out)
// mode 2: separate hi/lo [row][512] each   (for WMT)
__global__ __launch_bounds__(256) void sgemm_kernel(
        const unsigned short* __restrict__ Ah_g, const unsigned short* __restrict__ Al_g,
        const unsigned short* __restrict__ Bh_g, const unsigned short* __restrict__ Bl_g,
        const float* __restrict__ bias, int mode,
        unsigned short* __restrict__ out0, unsigned short* __restrict__ out2l,
        float* __restrict__ outf) {
    __shared__ unsigned short smem[16384];          // 32 KB
    unsigned short* Ah = smem;                      // [128][32]
    unsigned short* Al = smem + 4096;
    unsigned short* Bh = smem + 8192;
    unsigned short* Bl = smem + 12288;

    const int bn = blockIdx.x, bm = blockIdx.y;
    const int t = threadIdx.x, w = t >> 6, l = t & 63;
    const int wm = (w >> 1) * 64, wn = (w & 1) * 64;
    const int c16 = l & 15, q = l >> 4, q8 = q << 3;
    const int rB = l >> 2, cB = (l & 3) << 3;

    f32x4 acc[4][4];
#pragma unroll
    for (int i = 0; i < 4; ++i)
#pragma unroll
        for (int jj = 0; jj < 4; ++jj) acc[i][jj] = (f32x4){0.f,0.f,0.f,0.f};

    for (int k0 = 0; k0 < DM; k0 += 32) {
#pragma unroll
        for (int jj = 0; jj < 2; ++jj) {
            int r = w * 32 + jj * 16;
            size_t ga = (size_t)(bm * 128 + r + rB) * DM + k0 + cB;
            gld16(Ah_g + ga, &Ah[r * 32]);
            gld16(Al_g + ga, &Al[r * 32]);
            size_t gb = (size_t)(bn * 128 + r + rB) * DM + k0 + cB;
            gld16(Bh_g + gb, &Bh[r * 32]);
            gld16(Bl_g + gb, &Bl[r * 32]);
        }
        __syncthreads();
        bf16x8 ah[4], al[4];
#pragma unroll
        for (int mt = 0; mt < 4; ++mt) {
            ah[mt] = *(const bf16x8*)&Ah[(wm + mt*16 + c16) * 32 + q8];
            al[mt] = *(const bf16x8*)&Al[(wm + mt*16 + c16) * 32 + q8];
        }
#pragma unroll
        for (int nt = 0; nt < 4; ++nt) {
            bf16x8 bh = *(const bf16x8*)&Bh[(wn + nt*16 + c16) * 32 + q8];
            bf16x8 bl = *(const bf16x8*)&Bl[(wn + nt*16 + c16) * 32 + q8];
#pragma unroll
            for (int mt = 0; mt < 4; ++mt) {
                acc[mt][nt] = __builtin_amdgcn_mfma_f32_16x16x32_bf16(ah[mt], bh, acc[mt][nt], 0, 0, 0);
                acc[mt][nt] = __builtin_amdgcn_mfma_f32_16x16x32_bf16(al[mt], bh, acc[mt][nt], 0, 0, 0);
                acc[mt][nt] = __builtin_amdgcn_mfma_f32_16x16x32_bf16(ah[mt], bl, acc[mt][nt], 0, 0, 0);
            }
        }
        __syncthreads();
    }

#pragma unroll
    for (int mt = 0; mt < 4; ++mt)
#pragma unroll
        for (int nt = 0; nt < 4; ++nt) {
            int col = bn * 128 + wn + nt * 16 + c16;
            float bia = bias ? bias[col] : 0.f;
#pragma unroll
            for (int r = 0; r < 4; ++r) {
                size_t row = (size_t)bm * 128 + wm + mt * 16 + q * 4 + r;
                float y = acc[mt][nt][r] + bia;
                if (mode == 0) {
                    unsigned short h = f2bf(y);
                    out0[row * 1024 + col]       = h;
                    out0[row * 1024 + 512 + col] = f2bf(y - bf2f(h));
                } else if (mode == 1) {
                    outf[row * 512 + col] = y;
                } else {
                    unsigned short h = f2bf(y);
                    out0[row * 512 + col]  = h;
                    out2l[row * 512 + col] = f2bf(y - bf2f(h));
                }
            }
        }
}

// ---------------- x2 split + transpose --------------------------------------
// Per block: 128 keys x 128 dims. Writes:
//   x2m[key][0:512]=hi, [512:1024]=lo   (attn "K2" slot, row-major)
//   x2ht[d][key] = hi                    (attn "Vt" slot, transposed)
// LDS T is [d][key] stride 136, key-index XOR-swizzled by ((d>>2)&15)<<3 to
// break the 16-way write conflict while keeping 8-ushort runs contiguous
// (writer 4-way, reader 2-way — both cheap; kernel is HBM-bound anyway).
__global__ __launch_bounds__(256) void splitT_kernel(const float* __restrict__ src,
        unsigned short* __restrict__ x2m, unsigned short* __restrict__ x2ht) {
    __shared__ unsigned short T[128 * 136];
    const int d0 = blockIdx.x * 128, k0 = blockIdx.y * 128;
    const int t = threadIdx.x;
    const int cg = t & 31, rg = t >> 5;
#pragma unroll
    for (int i = 0; i < 16; ++i) {
        int row = i * 8 + rg;
        float4 v = *(const float4*)(src + (size_t)(k0 + row) * DM + d0 + cg * 4);
        float ff[4] = {v.x, v.y, v.z, v.w};
        u16x4 h, lo_;
#pragma unroll
        for (int j = 0; j < 4; ++j) {
            h[j]   = f2bf(ff[j]);
            lo_[j] = f2bf(ff[j] - bf2f(h[j]));
        }
        size_t gm = (size_t)(k0 + row) * 1024 + d0 + cg * 4;
        *(u16x4*)(x2m + gm)       = h;
        *(u16x4*)(x2m + gm + 512) = lo_;
        int rsw = row ^ ((cg & 15) << 3);   // (c>>2)&15 == cg for c = cg*4+j
#pragma unroll
        for (int j = 0; j < 4; ++j)
            T[(cg * 4 + j) * 136 + rsw] = h[j];
    }
    __syncthreads();
#pragma unroll
    for (int ii = 0; ii < 8; ++ii) {
        int dl = ii * 16 + (t >> 4);
        int ko = (t & 15) * 8;
        u16x8 vv = *(const u16x8*)&T[dl * 136 + (ko ^ (((dl >> 2) & 15) << 3))];
        *(u16x8*)(x2ht + (size_t)(d0 + dl) * KEYS_TOTAL + k0 + ko) = vv;
    }
}

// ---------------- fused attention: per (chunk, batch), CHUNK=256 ------------
// UNCHANGED from round 4 (harness-verified). Inputs re-bound:
//   Q2 := M2 [2048][1024] hi|lo; K2 := x2m; Vt := x2ht. Output U = P@x2.
__global__ __launch_bounds__(512, 4) void attn_kernel(
        const unsigned short* __restrict__ Q2,
        const unsigned short* __restrict__ K2,
        const unsigned short* __restrict__ Vt,
        float* __restrict__ Opart,                // [512][64][512]
        float* __restrict__ ML) {                 // [512][128] (m|l)
    __shared__ char smem_raw[69120];
    unsigned short* Qh = (unsigned short*)smem_raw;            // [64][32]
    unsigned short* Ql = (unsigned short*)(smem_raw + 4096);
    unsigned short* Kh = (unsigned short*)(smem_raw + 8192);   // [256][32]
    unsigned short* Kl = (unsigned short*)(smem_raw + 24576);
    unsigned short* Pb = (unsigned short*)smem_raw;            // [64][264]
    unsigned short* Vb = (unsigned short*)(smem_raw + 33792);  // [512][32]
    float* redb = (float*)(smem_raw + 66560);                  // [8][64]
    float* mrow = (float*)(smem_raw + 68608);                  // [64]
    float* lrow = (float*)(smem_raw + 68864);                  // [64]

    const int c = blockIdx.x, b = blockIdx.y;
    const int t = threadIdx.x, w = t >> 6, l = t & 63;
    const int c16 = l & 15, q = l >> 4, q8 = q << 3;
    const int rB = l >> 2, cB = (l & 3) << 3;
    const size_t key0 = (size_t)b * LKV + (size_t)c * CHUNK;

    f32x4 acc[4][2];
#pragma unroll
    for (int i = 0; i < 4; ++i)
#pragma unroll
        for (int jj = 0; jj < 2; ++jj) acc[i][jj] = (f32x4){0.f,0.f,0.f,0.f};

    // ---- QK: S[64 rows][256 keys]
    for (int k0 = 0; k0 < DM; k0 += 32) {
        if (w < 4)
            gld16(Q2 + (size_t)(b * 64 + w * 16 + rB) * 1024 + k0 + cB, &Qh[(w * 16) * 32]);
        else
            gld16(Q2 + (size_t)(b * 64 + (w - 4) * 16 + rB) * 1024 + 512 + k0 + cB, &Ql[((w - 4) * 16) * 32]);
#pragma unroll
        for (int jj = 0; jj < 2; ++jj) {
            int r = w * 32 + jj * 16;
            size_t krow = key0 + r + rB;
            gld16(K2 + krow * 1024 + k0 + cB,       &Kh[r * 32]);
            gld16(K2 + krow * 1024 + 512 + k0 + cB, &Kl[r * 32]);
        }
        __syncthreads();
        bf16x8 ah[4], al[4];
#pragma unroll
        for (int mt = 0; mt < 4; ++mt) {
            ah[mt] = *(const bf16x8*)&Qh[(mt * 16 + c16) * 32 + q8];
            al[mt] = *(const bf16x8*)&Ql[(mt * 16 + c16) * 32 + q8];
        }
#pragma unroll
        for (int nt = 0; nt < 2; ++nt) {
            bf16x8 bh = *(const bf16x8*)&Kh[(w * 32 + nt * 16 + c16) * 32 + q8];
            bf16x8 bl = *(const bf16x8*)&Kl[(w * 32 + nt * 16 + c16) * 32 + q8];
#pragma unroll
            for (int mt = 0; mt < 4; ++mt) {
                acc[mt][nt] = __builtin_amdgcn_mfma_f32_16x16x32_bf16(ah[mt], bh, acc[mt][nt], 0, 0, 0);
                acc[mt][nt] = __builtin_amdgcn_mfma_f32_16x16x32_bf16(al[mt], bh, acc[mt][nt], 0, 0, 0);
                acc[mt][nt] = __builtin_amdgcn_mfma_f32_16x16x32_bf16(ah[mt], bl, acc[mt][nt], 0, 0, 0);
            }
        }
        __syncthreads();
    }

    // ---- softmax over the chunk
#pragma unroll
    for (int mt = 0; mt < 4; ++mt)
#pragma unroll
        for (int nt = 0; nt < 2; ++nt)
#pragma unroll
            for (int r = 0; r < 4; ++r) acc[mt][nt][r] *= SCALE;

    float rmax_[4][4];
#pragma unroll
    for (int mt = 0; mt < 4; ++mt)
#pragma unroll
        for (int r = 0; r < 4; ++r)
            rmax_[mt][r] = fmaxf(acc[mt][0][r], acc[mt][1][r]);
#pragma unroll
    for (int off = 1; off < 16; off <<= 1)
#pragma unroll
        for (int mt = 0; mt < 4; ++mt)
#pragma unroll
            for (int r = 0; r < 4; ++r)
                rmax_[mt][r] = fmaxf(rmax_[mt][r], __shfl_xor(rmax_[mt][r], off));
    if (c16 == 0) {
#pragma unroll
        for (int mt = 0; mt < 4; ++mt)
#pragma unroll
            for (int r = 0; r < 4; ++r) redb[w * 64 + mt * 16 + q * 4 + r] = rmax_[mt][r];
    }
    __syncthreads();
    if (t < 64) {
        float m = redb[t];
#pragma unroll
        for (int ww = 1; ww < 8; ++ww) m = fmaxf(m, redb[ww * 64 + t]);
        mrow[t] = m;
    }
    __syncthreads();

    float rsum_[4][4];
#pragma unroll
    for (int mt = 0; mt < 4; ++mt)
#pragma unroll
        for (int r = 0; r < 4; ++r) {
            float m = mrow[mt * 16 + q * 4 + r];
            float s = 0.f;
#pragma unroll
            for (int nt = 0; nt < 2; ++nt) {
                float e = __expf(acc[mt][nt][r] - m);
                acc[mt][nt][r] = e;
                s += e;
            }
            rsum_[mt][r] = s;
        }
#pragma unroll
    for (int off = 1; off < 16; off <<= 1)
#pragma unroll
        for (int mt = 0; mt < 4; ++mt)
#pragma unroll
            for (int r = 0; r < 4; ++r) rsum_[mt][r] += __shfl_xor(rsum_[mt][r], off);
    if (c16 == 0) {
#pragma unroll
        for (int mt = 0; mt < 4; ++mt)
#pragma unroll
            for (int r = 0; r < 4; ++r) redb[w * 64 + mt * 16 + q * 4 + r] = rsum_[mt][r];
    }
    __syncthreads();
    if (t < 64) {
        float s = redb[t];
#pragma unroll
        for (int ww = 1; ww < 8; ++ww) s += redb[ww * 64 + t];
        lrow[t] = s;
    }
    // P -> LDS (bf16 row-major [row][key], stride PBS)
#pragma unroll
    for (int mt = 0; mt < 4; ++mt)
#pragma unroll
        for (int nt = 0; nt < 2; ++nt)
#pragma unroll
            for (int r = 0; r < 4; ++r)
                Pb[(mt * 16 + q * 4 + r) * PBS + w * 32 + nt * 16 + c16] = f2bf(acc[mt][nt][r]);
    __syncthreads();

    // ---- PV: U[64][512] = P @ x2_chunk
    f32x4 accO[4][4];
#pragma unroll
    for (int i = 0; i < 4; ++i)
#pragma unroll
        for (int jj = 0; jj < 4; ++jj) accO[i][jj] = (f32x4){0.f,0.f,0.f,0.f};

    for (int ks = 0; ks < CHUNK; ks += 32) {
#pragma unroll
        for (int jj = 0; jj < 4; ++jj) {
            int d = jj * 128 + w * 16;
            gld16(Vt + (size_t)(d + rB) * KEYS_TOTAL + key0 + ks + cB, &Vb[d * 32]);
        }
        __syncthreads();
        bf16x8 ap[4];
#pragma unroll
        for (int mt = 0; mt < 4; ++mt)
            ap[mt] = *(const bf16x8*)&Pb[(mt * 16 + c16) * PBS + ks + q8];
#pragma unroll
        for (int nt = 0; nt < 4; ++nt) {
            bf16x8 bv = *(const bf16x8*)&Vb[(w * 64 + nt * 16 + c16) * 32 + q8];
#pragma unroll
            for (int mt = 0; mt < 4; ++mt)
                accO[mt][nt] = __builtin_amdgcn_mfma_f32_16x16x32_bf16(ap[mt], bv, accO[mt][nt], 0, 0, 0);
        }
        __syncthreads();
    }

    const size_t part = (size_t)b * NCHUNK + c;
#pragma unroll
    for (int mt = 0; mt < 4; ++mt)
#pragma unroll
        for (int nt = 0; nt < 4; ++nt)
#pragma unroll
            for (int r = 0; r < 4; ++r)
                Opart[(part * 64 + mt * 16 + q * 4 + r) * 512 + w * 64 + nt * 16 + c16] = accO[mt][nt][r];
    if (t < 64) {
        ML[part * 128 + t]      = mrow[t];
        ML[part * 128 + 64 + t] = lrow[t];
    }
}

// ---------------- combine chunk partials -> U (bf16 hi/lo) ------------------
__global__ __launch_bounds__(128) void combine_kernel(const float* __restrict__ Opart,
                                                      const float* __restrict__ ML,
                                                      unsigned short* __restrict__ Uh,
                                                      unsigned short* __restrict__ Ul) {
    const int b = blockIdx.x >> 6, row = blockIdx.x & 63;
    const int t = threadIdx.x;
    float m[NCHUNK], lv[NCHUNK];
    float M = -1e30f;
#pragma unroll
    for (int c = 0; c < NCHUNK; ++c) {
        m[c]  = ML[(size_t)(b * NCHUNK + c) * 128 + row];
        lv[c] = ML[(size_t)(b * NCHUNK + c) * 128 + 64 + row];
        M = fmaxf(M, m[c]);
    }
    float den = 0.f, wgt[NCHUNK];
#pragma unroll
    for (int c = 0; c < NCHUNK; ++c) { wgt[c] = __expf(m[c] - M); den += wgt[c] * lv[c]; }
    float4 o = make_float4(0.f, 0.f, 0.f, 0.f);
#pragma unroll
    for (int c = 0; c < NCHUNK; ++c) {
        float4 v = *(const float4*)&Opart[((size_t)(b * NCHUNK + c) * 64 + row) * 512 + t * 4];
        o.x += wgt[c] * v.x; o.y += wgt[c] * v.y; o.z += wgt[c] * v.z; o.w += wgt[c] * v.w;
    }
    const float inv = 1.f / den;
    float rr[4] = {o.x * inv, o.y * inv, o.z * inv, o.w * inv};
    u16x4 h, lo_;
#pragma unroll
    for (int j = 0; j < 4; ++j) {
        h[j]   = f2bf(rr[j]);
        lo_[j] = f2bf(rr[j] - bf2f(h[j]));
    }
    size_t base = ((size_t)(b * 64 + row)) * 512 + t * 4;
    *(u16x4*)&Uh[base] = h;
    *(u16x4*)&Ul[base] = lo_;
}

extern "C" void kernel_launch(void* const* d_in, const int* in_sizes, int n_in,
                              void* d_out, int out_size, void* d_ws, size_t ws_size,
                              hipStream_t stream) {
    const float* x1 = (const float*)d_in[0];   // [32,64,512]
    const float* x2 = (const float*)d_in[1];   // [32,4096,512]
    const float* wq = (const float*)d_in[3];
    const float* bq = (const float*)d_in[4];
    const float* wk = (const float*)d_in[5];
    // bk (d_in[6]) is unused: its score contribution is a per-row constant,
    // exactly cancelled by softmax.
    const float* wv = (const float*)d_in[7];
    const float* bv = (const float*)d_in[8];
    float* out = (float*)d_out;

    char* ws = (char*)d_ws;
    unsigned short* x2m   = (unsigned short*)(ws);               // 268,435,456 B
    unsigned short* x2ht  = (unsigned short*)(ws + 268435456);   // 134,217,728 B
    float*          Opart = (float*)(ws + 402653184);            //  67,108,864 B
    float*          ML    = (float*)(ws + 469762048);            //     262,144 B
    unsigned short* M2    = (unsigned short*)(ws + 470024192);   //   4,194,304 B
    unsigned short* x1h   = (unsigned short*)(ws + 474218496);   //   2,097,152 B
    unsigned short* x1l   = (unsigned short*)(ws + 476315648);   //   2,097,152 B
    unsigned short* Uh    = (unsigned short*)(ws + 478412800);   //   2,097,152 B
    unsigned short* Ul    = (unsigned short*)(ws + 480509952);   //   2,097,152 B
    float*          Wqt   = (float*)(ws + 482607104);            //   1,048,576 B
    float*          Wkt   = (float*)(ws + 483655680);            //   1,048,576 B
    unsigned short* wqth  = (unsigned short*)(ws + 484704256);   //     524,288 B
    unsigned short* wqtl  = (unsigned short*)(ws + 485228544);
    unsigned short* wkth  = (unsigned short*)(ws + 485752832);
    unsigned short* wktl  = (unsigned short*)(ws + 486277120);
    unsigned short* wvh   = (unsigned short*)(ws + 486801408);
    unsigned short* wvl   = (unsigned short*)(ws + 487325696);
    unsigned short* WMTh  = (unsigned short*)(ws + 487849984);
    unsigned short* WMTl  = (unsigned short*)(ws + 488374272);
    float*          bM    = (float*)(ws + 488898560);            // end ~488.9 MB

    // --- x2 split + transpose (the only big streaming pass) ---
    splitT_kernel<<<dim3(4, 1024), 256, 0, stream>>>(x2, x2m, x2ht);

    // --- tiny weight-side chain: WMT[d,k] = sum_e Wq[e,k] Wk[e,d] ---
    transpose_kernel<<<dim3(8, 8), 256, 0, stream>>>(wq, Wqt);
    transpose_kernel<<<dim3(8, 8), 256, 0, stream>>>(wk, Wkt);
    bmfold_kernel<<<2, 256, 0, stream>>>(bq, wk, bM);
    split_kernel<<<128, 256, 0, stream>>>(Wqt, wqth, wqtl);
    split_kernel<<<128, 256, 0, stream>>>(Wkt, wkth, wktl);
    split_kernel<<<128, 256, 0, stream>>>(wv, wvh, wvl);
    split_kernel<<<512, 256, 0, stream>>>(x1, x1h, x1l);
    // WMT = Wkt @ Wqt^T  -> separate hi/lo
    sgemm_kernel<<<dim3(4, 4), 256, 0, stream>>>(wkth, wktl, wqth, wqtl,
                                                 nullptr, 2, WMTh, WMTl, nullptr);
    // M = x1 @ WMT^T + bM -> merged hi|lo (attn Q2 format)
    sgemm_kernel<<<dim3(4, 16), 256, 0, stream>>>(x1h, x1l, WMTh, WMTl,
                                                  bM, 0, M2, nullptr, nullptr);

    // --- fused attention (S = M @ x2^T, U = P @ x2) + combine ---
    attn_kernel<<<dim3(NCHUNK, NB), 512, 0, stream>>>(M2, x2m, x2ht, Opart, ML);
    combine_kernel<<<NB * LQ, 128, 0, stream>>>(Opart, ML, Uh, Ul);

    // --- out = U @ Wv^T + bv ---
    sgemm_kernel<<<dim3(4, 16), 256, 0, stream>>>(Uh, Ul, wvh, wvl,
                                                  bv, 1, nullptr, nullptr, out);
}

// Round 3
// 663.305 us; speedup vs baseline: 1.5683x; 1.0522x over previous
//
#include <hip/hip_runtime.h>
#include <math.h>

// Cross-attention forward, B=32, LQ=64, LKV=4096, D=512, fp32 in/out.
// Round 6 (resubmit — round 2 bench hit GPUAcquisitionTimeout, never ran):
//   - attn QK: double-buffered LDS staging (2x40KB, exactly 2 blocks/CU).
//     Stage(t+1) issued BEFORE compute(t); one barrier per K-step (was 2 +
//     serial load latency). Catalog T3 "minimum 2-phase" pattern.
//   - attn PV: V tile split into two 256-dim halves -> 2x16KB double buffer
//     fits alongside Pb. First stage issued before softmax (hides under
//     the reductions). accO indexed with compile-time h (two loops, rule #20).
//   - weight chain: q~ = x1 Wq^T + bq, then M = q~ @ Wk^T^T. Kills one
//     transpose, one split, and bmfold (bq folds via first GEMM's bias;
//     bk still cancelled by softmax). M2 produced right before attn (L2-hot).

#define LQ 64
#define LKV 4096
#define NB 32
#define DM 512
#define SCALE 22.627416997969522f   // sqrt(512)
#define KEYS_TOTAL (NB * LKV)       // 131072
#define NCHUNK 16                   // chunks per batch
#define CHUNK 256                   // keys per attn block
#define PBS 264                     // Pb row stride (ushorts)

typedef __attribute__((ext_vector_type(8))) short bf16x8;
typedef __attribute__((ext_vector_type(4))) float f32x4;
typedef __attribute__((ext_vector_type(8))) unsigned short u16x8;
typedef __attribute__((ext_vector_type(4))) unsigned short u16x4;

__device__ __forceinline__ unsigned short f2bf(float f) {   // RNE fp32->bf16
    unsigned u = __float_as_uint(f);
    u += 0x7fffu + ((u >> 16) & 1u);
    return (unsigned short)(u >> 16);
}
__device__ __forceinline__ float bf2f(unsigned short s) {
    return __uint_as_float(((unsigned)s) << 16);
}
__device__ __forceinline__ void gld16(const void* g, void* l) {
    __builtin_amdgcn_global_load_lds(
        (const __attribute__((address_space(1))) unsigned int*)g,
        (__attribute__((address_space(3))) unsigned int*)l, 16, 0, 0);
}

// ---------------- split: fp32 -> hi/lo bf16, 8 elems/thread -----------------
__global__ __launch_bounds__(256) void split_kernel(const float* __restrict__ src,
                                                    unsigned short* __restrict__ hi,
                                                    unsigned short* __restrict__ lo) {
    size_t idx = ((size_t)blockIdx.x * 256 + threadIdx.x) * 8;
    float4 a = *(const float4*)(src + idx);
    float4 b = *(const float4*)(src + idx + 4);
    float ff[8] = {a.x, a.y, a.z, a.w, b.x, b.y, b.z, b.w};
    u16x8 h, l;
#pragma unroll
    for (int i = 0; i < 8; ++i) {
        h[i] = f2bf(ff[i]);
        l[i] = f2bf(ff[i] - bf2f(h[i]));
    }
    *(u16x8*)(hi + idx) = h;
    *(u16x8*)(lo + idx) = l;
}

// ---------------- fp32 512x512 transpose + split to hi/lo bf16 --------------
__global__ __launch_bounds__(256) void transposeSplit_kernel(const float* __restrict__ in,
        unsigned short* __restrict__ hi, unsigned short* __restrict__ lo) {
    __shared__ float T[64 * 65];
    const int bx = blockIdx.x * 64, by = blockIdx.y * 64;
    const int t = threadIdx.x, col = t & 63, rg = t >> 6;
#pragma unroll
    for (int i = 0; i < 16; ++i) {
        int row = i * 4 + rg;
        T[col * 65 + row] = in[(size_t)(by + row) * DM + bx + col];
    }
    __syncthreads();
#pragma unroll
    for (int i = 0; i < 16; ++i) {
        int row = i * 4 + rg;
        float v = T[row * 65 + col];
        unsigned short h = f2bf(v);
        hi[(size_t)(bx + row) * DM + by + col] = h;
        lo[(size_t)(bx + row) * DM + by + col] = f2bf(v - bf2f(h));
    }
}

// ---------------- small 3-term split-precision GEMM -------------------------
// out[row,col] = sum_k A[row,k]*B[col,k] + bias[col], A/B in hi/lo bf16 pairs.
// BM=BN=128, BK=32, 256 thr (4 waves 2x2), 16x16x32 bf16. K = DM = 512.
// mode 0: merged hi|lo output [row][1024]  (attn Q2 format)
// mode 1: fp32 output [row][512]           (final out)
// mode 2: separate hi/lo [row][512] each
__global__ __launch_bounds__(256) void sgemm_kernel(
        const unsigned short* __restrict__ Ah_g, const unsigned short* __restrict__ Al_g,
        const unsigned short* __restrict__ Bh_g, const unsigned short* __restrict__ Bl_g,
        const float* __restrict__ bias, int mode,
        unsigned short* __restrict__ out0, unsigned short* __restrict__ out2l,
        float* __restrict__ outf) {
    __shared__ unsigned short smem[16384];          // 32 KB
    unsigned short* Ah = smem;                      // [128][32]
    unsigned short* Al = smem + 4096;
    unsigned short* Bh = smem + 8192;
    unsigned short* Bl = smem + 12288;

    const int bn = blockIdx.x, bm = blockIdx.y;
    const int t = threadIdx.x, w = t >> 6, l = t & 63;
    const int wm = (w >> 1) * 64, wn = (w & 1) * 64;
    const int c16 = l & 15, q = l >> 4, q8 = q << 3;
    const int rB = l >> 2, cB = (l & 3) << 3;

    f32x4 acc[4][4];
#pragma unroll
    for (int i = 0; i < 4; ++i)
#pragma unroll
        for (int jj = 0; jj < 4; ++jj) acc[i][jj] = (f32x4){0.f,0.f,0.f,0.f};

    for (int k0 = 0; k0 < DM; k0 += 32) {
#pragma unroll
        for (int jj = 0; jj < 2; ++jj) {
            int r = w * 32 + jj * 16;
            size_t ga = (size_t)(bm * 128 + r + rB) * DM + k0 + cB;
            gld16(Ah_g + ga, &Ah[r * 32]);
            gld16(Al_g + ga, &Al[r * 32]);
            size_t gb = (size_t)(bn * 128 + r + rB) * DM + k0 + cB;
            gld16(Bh_g + gb, &Bh[r * 32]);
            gld16(Bl_g + gb, &Bl[r * 32]);
        }
        __syncthreads();
        bf16x8 ah[4], al[4];
#pragma unroll
        for (int mt = 0; mt < 4; ++mt) {
            ah[mt] = *(const bf16x8*)&Ah[(wm + mt*16 + c16) * 32 + q8];
            al[mt] = *(const bf16x8*)&Al[(wm + mt*16 + c16) * 32 + q8];
        }
#pragma unroll
        for (int nt = 0; nt < 4; ++nt) {
            bf16x8 bh = *(const bf16x8*)&Bh[(wn + nt*16 + c16) * 32 + q8];
            bf16x8 bl = *(const bf16x8*)&Bl[(wn + nt*16 + c16) * 32 + q8];
#pragma unroll
            for (int mt = 0; mt < 4; ++mt) {
                acc[mt][nt] = __builtin_amdgcn_mfma_f32_16x16x32_bf16(ah[mt], bh, acc[mt][nt], 0, 0, 0);
                acc[mt][nt] = __builtin_amdgcn_mfma_f32_16x16x32_bf16(al[mt], bh, acc[mt][nt], 0, 0, 0);
                acc[mt][nt] = __builtin_amdgcn_mfma_f32_16x16x32_bf16(ah[mt], bl, acc[mt][nt], 0, 0, 0);
            }
        }
        __syncthreads();
    }

#pragma unroll
    for (int mt = 0; mt < 4; ++mt)
#pragma unroll
        for (int nt = 0; nt < 4; ++nt) {
            int col = bn * 128 + wn + nt * 16 + c16;
            float bia = bias ? bias[col] : 0.f;
#pragma unroll
            for (int r = 0; r < 4; ++r) {
                size_t row = (size_t)bm * 128 + wm + mt * 16 + q * 4 + r;
                float y = acc[mt][nt][r] + bia;
                if (mode == 0) {
                    unsigned short h = f2bf(y);
                    out0[row * 1024 + col]       = h;
                    out0[row * 1024 + 512 + col] = f2bf(y - bf2f(h));
                } else if (mode == 1) {
                    outf[row * 512 + col] = y;
                } else {
                    unsigned short h = f2bf(y);
                    out0[row * 512 + col]  = h;
                    out2l[row * 512 + col] = f2bf(y - bf2f(h));
                }
            }
        }
}

// ---------------- x2 split + transpose --------------------------------------
__global__ __launch_bounds__(256) void splitT_kernel(const float* __restrict__ src,
        unsigned short* __restrict__ x2m, unsigned short* __restrict__ x2ht) {
    __shared__ unsigned short T[128 * 136];
    const int d0 = blockIdx.x * 128, k0 = blockIdx.y * 128;
    const int t = threadIdx.x;
    const int cg = t & 31, rg = t >> 5;
#pragma unroll
    for (int i = 0; i < 16; ++i) {
        int row = i * 8 + rg;
        float4 v = *(const float4*)(src + (size_t)(k0 + row) * DM + d0 + cg * 4);
        float ff[4] = {v.x, v.y, v.z, v.w};
        u16x4 h, lo_;
#pragma unroll
        for (int j = 0; j < 4; ++j) {
            h[j]   = f2bf(ff[j]);
            lo_[j] = f2bf(ff[j] - bf2f(h[j]));
        }
        size_t gm = (size_t)(k0 + row) * 1024 + d0 + cg * 4;
        *(u16x4*)(x2m + gm)       = h;
        *(u16x4*)(x2m + gm + 512) = lo_;
        int rsw = row ^ ((cg & 15) << 3);
#pragma unroll
        for (int j = 0; j < 4; ++j)
            T[(cg * 4 + j) * 136 + rsw] = h[j];
    }
    __syncthreads();
#pragma unroll
    for (int ii = 0; ii < 8; ++ii) {
        int dl = ii * 16 + (t >> 4);
        int ko = (t & 15) * 8;
        u16x8 vv = *(const u16x8*)&T[dl * 136 + (ko ^ (((dl >> 2) & 15) << 3))];
        *(u16x8*)(x2ht + (size_t)(d0 + dl) * KEYS_TOTAL + k0 + ko) = vv;
    }
}

// ---------------- fused attention: per (chunk, batch), CHUNK=256 ------------
// QK double-buffered: buf s at s*40960 {Qh 4K | Ql 4K | Kh 16K | Kl 16K}.
// PV aliases: Pb@0 (33792) | Vb[s]@33792+s*16384 | redb@66560 | mrow/lrow.
// PV splits dims into halves h=0,1 (wave w owns dims h*256 + w*32 .. +32).
__global__ __launch_bounds__(512, 4) void attn_kernel(
        const unsigned short* __restrict__ Q2,    // [2048][1024] hi|lo (M)
        const unsigned short* __restrict__ K2,    // [131072][1024] hi|lo (x2)
        const unsigned short* __restrict__ Vt,    // [512][131072] (x2^T hi)
        float* __restrict__ Opart,                // [512][64][512]
        float* __restrict__ ML) {                 // [512][128] (m|l)
    __shared__ char smem_raw[81920];
    unsigned short* Pb = (unsigned short*)smem_raw;            // [64][264]
    float* redb = (float*)(smem_raw + 66560);                  // [8][64]
    float* mrow = (float*)(smem_raw + 68608);                  // [64]
    float* lrow = (float*)(smem_raw + 68864);                  // [64]

    const int c = blockIdx.x, b = blockIdx.y;
    const int t = threadIdx.x, w = t >> 6, l = t & 63;
    const int c16 = l & 15, q = l >> 4, q8 = q << 3;
    const int rB = l >> 2, cB = (l & 3) << 3;
    const size_t key0 = (size_t)b * LKV + (size_t)c * CHUNK;

    f32x4 acc[4][2];
#pragma unroll
    for (int i = 0; i < 4; ++i)
#pragma unroll
        for (int jj = 0; jj < 2; ++jj) acc[i][jj] = (f32x4){0.f,0.f,0.f,0.f};

    auto stageQK = [&](int s, int k0) {
        char* base = smem_raw + s * 40960;
        unsigned short* Qh = (unsigned short*)base;
        unsigned short* Ql = (unsigned short*)(base + 4096);
        unsigned short* Kh = (unsigned short*)(base + 8192);
        unsigned short* Kl = (unsigned short*)(base + 24576);
        if (w < 4)
            gld16(Q2 + (size_t)(b * 64 + w * 16 + rB) * 1024 + k0 + cB, &Qh[(w * 16) * 32]);
        else
            gld16(Q2 + (size_t)(b * 64 + (w - 4) * 16 + rB) * 1024 + 512 + k0 + cB, &Ql[((w - 4) * 16) * 32]);
#pragma unroll
        for (int jj = 0; jj < 2; ++jj) {
            int r = w * 32 + jj * 16;
            size_t krow = key0 + r + rB;
            gld16(K2 + krow * 1024 + k0 + cB,       &Kh[r * 32]);
            gld16(K2 + krow * 1024 + 512 + k0 + cB, &Kl[r * 32]);
        }
    };

    // ---- QK: S[64 rows][256 keys], pipelined staging
    stageQK(0, 0);
    __syncthreads();
#pragma unroll 1
    for (int k0 = 0; k0 < DM; k0 += 32) {
        const int s = (k0 >> 5) & 1;
        if (k0 + 32 < DM) stageQK(s ^ 1, k0 + 32);
        const unsigned short* Qh = (const unsigned short*)(smem_raw + s * 40960);
        const unsigned short* Ql = Qh + 2048;
        const unsigned short* Kh = Qh + 4096;
        const unsigned short* Kl = Qh + 12288;
        bf16x8 ah[4], al[4];
#pragma unroll
        for (int mt = 0; mt < 4; ++mt) {
            ah[mt] = *(const bf16x8*)&Qh[(mt * 16 + c16) * 32 + q8];
            al[mt] = *(const bf16x8*)&Ql[(mt * 16 + c16) * 32 + q8];
        }
#pragma unroll
        for (int nt = 0; nt < 2; ++nt) {
            bf16x8 bh = *(const bf16x8*)&Kh[(w * 32 + nt * 16 + c16) * 32 + q8];
            bf16x8 bl = *(const bf16x8*)&Kl[(w * 32 + nt * 16 + c16) * 32 + q8];
#pragma unroll
            for (int mt = 0; mt < 4; ++mt) {
                acc[mt][nt] = __builtin_amdgcn_mfma_f32_16x16x32_bf16(ah[mt], bh, acc[mt][nt], 0, 0, 0);
                acc[mt][nt] = __builtin_amdgcn_mfma_f32_16x16x32_bf16(al[mt], bh, acc[mt][nt], 0, 0, 0);
                acc[mt][nt] = __builtin_amdgcn_mfma_f32_16x16x32_bf16(ah[mt], bl, acc[mt][nt], 0, 0, 0);
            }
        }
        __syncthreads();
    }

    auto stagePV = [&](int s, int h, int ks) {
        unsigned short* Vb = (unsigned short*)(smem_raw + 33792 + s * 16384);
#pragma unroll
        for (int jj = 0; jj < 2; ++jj) {
            int dloc = w * 32 + jj * 16;
            gld16(Vt + (size_t)(h * 256 + dloc + rB) * KEYS_TOTAL + key0 + ks * 32 + cB,
                  &Vb[dloc * 32]);
        }
    };
    // first PV stage rides under the softmax reductions (Vb region is free
    // after the QK loop's final barrier; Pb/redb writes don't touch it)
    stagePV(0, 0, 0);

    // ---- softmax over the chunk
#pragma unroll
    for (int mt = 0; mt < 4; ++mt)
#pragma unroll
        for (int nt = 0; nt < 2; ++nt)
#pragma unroll
            for (int r = 0; r < 4; ++r) acc[mt][nt][r] *= SCALE;

    float rmax_[4][4];
#pragma unroll
    for (int mt = 0; mt < 4; ++mt)
#pragma unroll
        for (int r = 0; r < 4; ++r)
            rmax_[mt][r] = fmaxf(acc[mt][0][r], acc[mt][1][r]);
#pragma unroll
    for (int off = 1; off < 16; off <<= 1)
#pragma unroll
        for (int mt = 0; mt < 4; ++mt)
#pragma unroll
            for (int r = 0; r < 4; ++r)
                rmax_[mt][r] = fmaxf(rmax_[mt][r], __shfl_xor(rmax_[mt][r], off));
    if (c16 == 0) {
#pragma unroll
        for (int mt = 0; mt < 4; ++mt)
#pragma unroll
            for (int r = 0; r < 4; ++r) redb[w * 64 + mt * 16 + q * 4 + r] = rmax_[mt][r];
    }
    __syncthreads();
    if (t < 64) {
        float m = redb[t];
#pragma unroll
        for (int ww = 1; ww < 8; ++ww) m = fmaxf(m, redb[ww * 64 + t]);
        mrow[t] = m;
    }
    __syncthreads();

    float rsum_[4][4];
#pragma unroll
    for (int mt = 0; mt < 4; ++mt)
#pragma unroll
        for (int r = 0; r < 4; ++r) {
            float m = mrow[mt * 16 + q * 4 + r];
            float s = 0.f;
#pragma unroll
            for (int nt = 0; nt < 2; ++nt) {
                float e = __expf(acc[mt][nt][r] - m);
                acc[mt][nt][r] = e;
                s += e;
            }
            rsum_[mt][r] = s;
        }
#pragma unroll
    for (int off = 1; off < 16; off <<= 1)
#pragma unroll
        for (int mt = 0; mt < 4; ++mt)
#pragma unroll
            for (int r = 0; r < 4; ++r) rsum_[mt][r] += __shfl_xor(rsum_[mt][r], off);
    if (c16 == 0) {
#pragma unroll
        for (int mt = 0; mt < 4; ++mt)
#pragma unroll
            for (int r = 0; r < 4; ++r) redb[w * 64 + mt * 16 + q * 4 + r] = rsum_[mt][r];
    }
    __syncthreads();
    if (t < 64) {
        float s = redb[t];
#pragma unroll
        for (int ww = 1; ww < 8; ++ww) s += redb[ww * 64 + t];
        lrow[t] = s;
    }
    // P -> LDS (bf16 row-major [row][key], stride PBS)
#pragma unroll
    for (int mt = 0; mt < 4; ++mt)
#pragma unroll
        for (int nt = 0; nt < 2; ++nt)
#pragma unroll
            for (int r = 0; r < 4; ++r)
                Pb[(mt * 16 + q * 4 + r) * PBS + w * 32 + nt * 16 + c16] = f2bf(acc[mt][nt][r]);
    __syncthreads();

    // ---- PV: U[64][512] = P @ x2_chunk, pipelined staging, dim-halves
    f32x4 accO[4][4];
#pragma unroll
    for (int i = 0; i < 4; ++i)
#pragma unroll
        for (int jj = 0; jj < 4; ++jj) accO[i][jj] = (f32x4){0.f,0.f,0.f,0.f};

#pragma unroll 1
    for (int ks = 0; ks < 8; ++ks) {          // h = 0 (dims 0..255)
        const int s = ks & 1;
        if (ks < 7) stagePV(s ^ 1, 0, ks + 1);
        else        stagePV(s ^ 1, 1, 0);
        const unsigned short* Vb = (const unsigned short*)(smem_raw + 33792 + s * 16384);
        bf16x8 ap[4];
#pragma unroll
        for (int mt = 0; mt < 4; ++mt)
            ap[mt] = *(const bf16x8*)&Pb[(mt * 16 + c16) * PBS + ks * 32 + q8];
#pragma unroll
        for (int nt = 0; nt < 2; ++nt) {
            bf16x8 bvv = *(const bf16x8*)&Vb[(w * 32 + nt * 16 + c16) * 32 + q8];
#pragma unroll
            for (int mt = 0; mt < 4; ++mt)
                accO[mt][nt] = __builtin_amdgcn_mfma_f32_16x16x32_bf16(ap[mt], bvv, accO[mt][nt], 0, 0, 0);
        }
        __syncthreads();
    }
#pragma unroll 1
    for (int ks = 0; ks < 8; ++ks) {          // h = 1 (dims 256..511)
        const int s = ks & 1;
        if (ks < 7) stagePV(s ^ 1, 1, ks + 1);
        const unsigned short* Vb = (const unsigned short*)(smem_raw + 33792 + s * 16384);
        bf16x8 ap[4];
#pragma unroll
        for (int mt = 0; mt < 4; ++mt)
            ap[mt] = *(const bf16x8*)&Pb[(mt * 16 + c16) * PBS + ks * 32 + q8];
#pragma unroll
        for (int nt = 0; nt < 2; ++nt) {
            bf16x8 bvv = *(const bf16x8*)&Vb[(w * 32 + nt * 16 + c16) * 32 + q8];
#pragma unroll
            for (int mt = 0; mt < 4; ++mt)
                accO[mt][2 + nt] = __builtin_amdgcn_mfma_f32_16x16x32_bf16(ap[mt], bvv, accO[mt][2 + nt], 0, 0, 0);
        }
        __syncthreads();
    }

    const size_t part = (size_t)b * NCHUNK + c;
#pragma unroll
    for (int mt = 0; mt < 4; ++mt)
#pragma unroll
        for (int h = 0; h < 2; ++h)
#pragma unroll
            for (int nt = 0; nt < 2; ++nt) {
                int col = h * 256 + w * 32 + nt * 16 + c16;
#pragma unroll
                for (int r = 0; r < 4; ++r)
                    Opart[(part * 64 + mt * 16 + q * 4 + r) * 512 + col] = accO[mt][h * 2 + nt][r];
            }
    if (t < 64) {
        ML[part * 128 + t]      = mrow[t];
        ML[part * 128 + 64 + t] = lrow[t];
    }
}

// ---------------- combine chunk partials -> U (bf16 hi/lo) ------------------
__global__ __launch_bounds__(128) void combine_kernel(const float* __restrict__ Opart,
                                                      const float* __restrict__ ML,
                                                      unsigned short* __restrict__ Uh,
                                                      unsigned short* __restrict__ Ul) {
    const int b = blockIdx.x >> 6, row = blockIdx.x & 63;
    const int t = threadIdx.x;
    float m[NCHUNK], lv[NCHUNK];
    float M = -1e30f;
#pragma unroll
    for (int c = 0; c < NCHUNK; ++c) {
        m[c]  = ML[(size_t)(b * NCHUNK + c) * 128 + row];
        lv[c] = ML[(size_t)(b * NCHUNK + c) * 128 + 64 + row];
        M = fmaxf(M, m[c]);
    }
    float den = 0.f, wgt[NCHUNK];
#pragma unroll
    for (int c = 0; c < NCHUNK; ++c) { wgt[c] = __expf(m[c] - M); den += wgt[c] * lv[c]; }
    float4 o = make_float4(0.f, 0.f, 0.f, 0.f);
#pragma unroll
    for (int c = 0; c < NCHUNK; ++c) {
        float4 v = *(const float4*)&Opart[((size_t)(b * NCHUNK + c) * 64 + row) * 512 + t * 4];
        o.x += wgt[c] * v.x; o.y += wgt[c] * v.y; o.z += wgt[c] * v.z; o.w += wgt[c] * v.w;
    }
    const float inv = 1.f / den;
    float rr[4] = {o.x * inv, o.y * inv, o.z * inv, o.w * inv};
    u16x4 h, lo_;
#pragma unroll
    for (int j = 0; j < 4; ++j) {
        h[j]   = f2bf(rr[j]);
        lo_[j] = f2bf(rr[j] - bf2f(h[j]));
    }
    size_t base = ((size_t)(b * 64 + row)) * 512 + t * 4;
    *(u16x4*)&Uh[base] = h;
    *(u16x4*)&Ul[base] = lo_;
}

extern "C" void kernel_launch(void* const* d_in, const int* in_sizes, int n_in,
                              void* d_out, int out_size, void* d_ws, size_t ws_size,
                              hipStream_t stream) {
    const float* x1 = (const float*)d_in[0];   // [32,64,512]
    const float* x2 = (const float*)d_in[1];   // [32,4096,512]
    const float* wq = (const float*)d_in[3];
    const float* bq = (const float*)d_in[4];
    const float* wk = (const float*)d_in[5];
    // bk (d_in[6]) unused: per-row constant in scores, cancelled by softmax.
    const float* wv = (const float*)d_in[7];
    const float* bv = (const float*)d_in[8];
    float* out = (float*)d_out;

    char* ws = (char*)d_ws;
    unsigned short* x2m   = (unsigned short*)(ws);               // 268,435,456 B
    unsigned short* x2ht  = (unsigned short*)(ws + 268435456);   // 134,217,728 B
    float*          Opart = (float*)(ws + 402653184);            //  67,108,864 B
    float*          ML    = (float*)(ws + 469762048);            //     262,144 B
    unsigned short* M2    = (unsigned short*)(ws + 470024192);   //   4,194,304 B
    unsigned short* x1h   = (unsigned short*)(ws + 474218496);   //   2,097,152 B
    unsigned short* x1l   = (unsigned short*)(ws + 476315648);   //   2,097,152 B
    unsigned short* Uh    = (unsigned short*)(ws + 478412800);   //   2,097,152 B
    unsigned short* Ul    = (unsigned short*)(ws + 480509952);   //   2,097,152 B
    unsigned short* q1h   = (unsigned short*)(ws + 482607104);   //   2,097,152 B
    unsigned short* q1l   = (unsigned short*)(ws + 484704256);   //   2,097,152 B
    unsigned short* wqh   = (unsigned short*)(ws + 486801408);   //     524,288 B
    unsigned short* wql   = (unsigned short*)(ws + 487325696);
    unsigned short* wkth  = (unsigned short*)(ws + 487849984);
    unsigned short* wktl  = (unsigned short*)(ws + 488374272);
    unsigned short* wvh   = (unsigned short*)(ws + 488898560);
    unsigned short* wvl   = (unsigned short*)(ws + 489422848);   // end 489,947,136

    // --- x2 split + transpose (the big streaming pass) ---
    splitT_kernel<<<dim3(4, 1024), 256, 0, stream>>>(x2, x2m, x2ht);

    // --- weight chain: q~ = x1 Wq^T + bq ; M = q~ @ Wk ---
    split_kernel<<<512, 256, 0, stream>>>(x1, x1h, x1l);
    split_kernel<<<128, 256, 0, stream>>>(wq, wqh, wql);
    transposeSplit_kernel<<<dim3(8, 8), 256, 0, stream>>>(wk, wkth, wktl);
    split_kernel<<<128, 256, 0, stream>>>(wv, wvh, wvl);
    sgemm_kernel<<<dim3(4, 16), 256, 0, stream>>>(x1h, x1l, wqh, wql,
                                                  bq, 2, q1h, q1l, nullptr);
    sgemm_kernel<<<dim3(4, 16), 256, 0, stream>>>(q1h, q1l, wkth, wktl,
                                                  nullptr, 0, M2, nullptr, nullptr);

    // --- fused attention (S = M @ x2^T, U = P @ x2) + combine ---
    attn_kernel<<<dim3(NCHUNK, NB), 512, 0, stream>>>(M2, x2m, x2ht, Opart, ML);
    combine_kernel<<<NB * LQ, 128, 0, stream>>>(Opart, ML, Uh, Ul);

    // --- out = U @ Wv^T + bv ---
    sgemm_kernel<<<dim3(4, 16), 256, 0, stream>>>(Uh, Ul, wvh, wvl,
                                                  bv, 1, nullptr, nullptr, out);
}

// Round 6
// 596.279 us; speedup vs baseline: 1.7446x; 1.1124x over previous
//
#include <hip/hip_runtime.h>
#include <math.h>

// Cross-attention forward, B=32, LQ=64, LKV=4096, D=512, fp32 in/out.
// Round 7 (2nd resubmit — infra failures: acquisition timeout, container
// failed twice, acquisition timeout again; kernel has never run):
//   - attn QK stages RAW fp32 x2 tiles ([256][32] fp32 = 32 KB = same bytes
//     as the old hi|lo bf16 pair) and does the hi/lo split in-register with
//     the exact f2bf math splitT used -> numerics identical, -536 MB HBM.
//   - splitT -> prepVt: transpose-only (reads x2 fp32, writes x2ht hi bf16).
//   - split(x1)/split(wq)/transposeSplit(wk)/split(wv) merged into one
//     prep_kernel (block-range dispatch): 4 launches -> 1.
//   - attn QK/PV double-buffer structure unchanged from round 6 (verified,
//     663 us).

#define LQ 64
#define LKV 4096
#define NB 32
#define DM 512
#define SCALE 22.627416997969522f   // sqrt(512)
#define KEYS_TOTAL (NB * LKV)       // 131072
#define NCHUNK 16                   // chunks per batch
#define CHUNK 256                   // keys per attn block
#define PBS 264                     // Pb row stride (ushorts)

typedef __attribute__((ext_vector_type(8))) short bf16x8;
typedef __attribute__((ext_vector_type(4))) float f32x4;
typedef __attribute__((ext_vector_type(8))) unsigned short u16x8;
typedef __attribute__((ext_vector_type(4))) unsigned short u16x4;

__device__ __forceinline__ unsigned short f2bf(float f) {   // RNE fp32->bf16
    unsigned u = __float_as_uint(f);
    u += 0x7fffu + ((u >> 16) & 1u);
    return (unsigned short)(u >> 16);
}
__device__ __forceinline__ float bf2f(unsigned short s) {
    return __uint_as_float(((unsigned)s) << 16);
}
__device__ __forceinline__ void gld16(const void* g, void* l) {
    __builtin_amdgcn_global_load_lds(
        (const __attribute__((address_space(1))) unsigned int*)g,
        (__attribute__((address_space(3))) unsigned int*)l, 16, 0, 0);
}

// ---------------- merged prep: splits + wk transpose-split ------------------
__device__ __forceinline__ void split8_body(const float* __restrict__ src,
                                            unsigned short* __restrict__ hi,
                                            unsigned short* __restrict__ lo, int blk) {
    size_t idx = ((size_t)blk * 256 + threadIdx.x) * 8;
    float4 a = *(const float4*)(src + idx);
    float4 b = *(const float4*)(src + idx + 4);
    float ff[8] = {a.x, a.y, a.z, a.w, b.x, b.y, b.z, b.w};
    u16x8 h, l;
#pragma unroll
    for (int i = 0; i < 8; ++i) {
        h[i] = f2bf(ff[i]);
        l[i] = f2bf(ff[i] - bf2f(h[i]));
    }
    *(u16x8*)(hi + idx) = h;
    *(u16x8*)(lo + idx) = l;
}

__global__ __launch_bounds__(256) void prep_kernel(
        const float* __restrict__ x1, const float* __restrict__ wq,
        const float* __restrict__ wk, const float* __restrict__ wv,
        unsigned short* __restrict__ x1h, unsigned short* __restrict__ x1l,
        unsigned short* __restrict__ wqh, unsigned short* __restrict__ wql,
        unsigned short* __restrict__ wkth, unsigned short* __restrict__ wktl,
        unsigned short* __restrict__ wvh, unsigned short* __restrict__ wvl) {
    __shared__ float T[64 * 65];
    int bid = blockIdx.x;
    if (bid < 512) { split8_body(x1, x1h, x1l, bid); return; }
    bid -= 512;
    if (bid < 128) { split8_body(wq, wqh, wql, bid); return; }
    bid -= 128;
    if (bid < 64) {   // transpose+split wk -> wkt hi/lo
        const int bx = (bid & 7) * 64, by = (bid >> 3) * 64;
        const int t = threadIdx.x, col = t & 63, rg = t >> 6;
#pragma unroll
        for (int i = 0; i < 16; ++i) {
            int row = i * 4 + rg;
            T[col * 65 + row] = wk[(size_t)(by + row) * DM + bx + col];
        }
        __syncthreads();
#pragma unroll
        for (int i = 0; i < 16; ++i) {
            int row = i * 4 + rg;
            float v = T[row * 65 + col];
            unsigned short h = f2bf(v);
            wkth[(size_t)(bx + row) * DM + by + col] = h;
            wktl[(size_t)(bx + row) * DM + by + col] = f2bf(v - bf2f(h));
        }
        return;
    }
    bid -= 64;
    split8_body(wv, wvh, wvl, bid);
}

// ---------------- small 3-term split-precision GEMM -------------------------
// out[row,col] = sum_k A[row,k]*B[col,k] + bias[col], A/B in hi/lo bf16 pairs.
// BM=BN=128, BK=32, 256 thr (4 waves 2x2), 16x16x32 bf16. K = DM = 512.
// mode 0: merged hi|lo output [row][1024]  (attn Q2 format)
// mode 1: fp32 output [row][512]           (final out)
// mode 2: separate hi/lo [row][512] each
__global__ __launch_bounds__(256) void sgemm_kernel(
        const unsigned short* __restrict__ Ah_g, const unsigned short* __restrict__ Al_g,
        const unsigned short* __restrict__ Bh_g, const unsigned short* __restrict__ Bl_g,
        const float* __restrict__ bias, int mode,
        unsigned short* __restrict__ out0, unsigned short* __restrict__ out2l,
        float* __restrict__ outf) {
    __shared__ unsigned short smem[16384];          // 32 KB
    unsigned short* Ah = smem;                      // [128][32]
    unsigned short* Al = smem + 4096;
    unsigned short* Bh = smem + 8192;
    unsigned short* Bl = smem + 12288;

    const int bn = blockIdx.x, bm = blockIdx.y;
    const int t = threadIdx.x, w = t >> 6, l = t & 63;
    const int wm = (w >> 1) * 64, wn = (w & 1) * 64;
    const int c16 = l & 15, q = l >> 4, q8 = q << 3;
    const int rB = l >> 2, cB = (l & 3) << 3;

    f32x4 acc[4][4];
#pragma unroll
    for (int i = 0; i < 4; ++i)
#pragma unroll
        for (int jj = 0; jj < 4; ++jj) acc[i][jj] = (f32x4){0.f,0.f,0.f,0.f};

    for (int k0 = 0; k0 < DM; k0 += 32) {
#pragma unroll
        for (int jj = 0; jj < 2; ++jj) {
            int r = w * 32 + jj * 16;
            size_t ga = (size_t)(bm * 128 + r + rB) * DM + k0 + cB;
            gld16(Ah_g + ga, &Ah[r * 32]);
            gld16(Al_g + ga, &Al[r * 32]);
            size_t gb = (size_t)(bn * 128 + r + rB) * DM + k0 + cB;
            gld16(Bh_g + gb, &Bh[r * 32]);
            gld16(Bl_g + gb, &Bl[r * 32]);
        }
        __syncthreads();
        bf16x8 ah[4], al[4];
#pragma unroll
        for (int mt = 0; mt < 4; ++mt) {
            ah[mt] = *(const bf16x8*)&Ah[(wm + mt*16 + c16) * 32 + q8];
            al[mt] = *(const bf16x8*)&Al[(wm + mt*16 + c16) * 32 + q8];
        }
#pragma unroll
        for (int nt = 0; nt < 4; ++nt) {
            bf16x8 bh = *(const bf16x8*)&Bh[(wn + nt*16 + c16) * 32 + q8];
            bf16x8 bl = *(const bf16x8*)&Bl[(wn + nt*16 + c16) * 32 + q8];
#pragma unroll
            for (int mt = 0; mt < 4; ++mt) {
                acc[mt][nt] = __builtin_amdgcn_mfma_f32_16x16x32_bf16(ah[mt], bh, acc[mt][nt], 0, 0, 0);
                acc[mt][nt] = __builtin_amdgcn_mfma_f32_16x16x32_bf16(al[mt], bh, acc[mt][nt], 0, 0, 0);
                acc[mt][nt] = __builtin_amdgcn_mfma_f32_16x16x32_bf16(ah[mt], bl, acc[mt][nt], 0, 0, 0);
            }
        }
        __syncthreads();
    }

#pragma unroll
    for (int mt = 0; mt < 4; ++mt)
#pragma unroll
        for (int nt = 0; nt < 4; ++nt) {
            int col = bn * 128 + wn + nt * 16 + c16;
            float bia = bias ? bias[col] : 0.f;
#pragma unroll
            for (int r = 0; r < 4; ++r) {
                size_t row = (size_t)bm * 128 + wm + mt * 16 + q * 4 + r;
                float y = acc[mt][nt][r] + bia;
                if (mode == 0) {
                    unsigned short h = f2bf(y);
                    out0[row * 1024 + col]       = h;
                    out0[row * 1024 + 512 + col] = f2bf(y - bf2f(h));
                } else if (mode == 1) {
                    outf[row * 512 + col] = y;
                } else {
                    unsigned short h = f2bf(y);
                    out0[row * 512 + col]  = h;
                    out2l[row * 512 + col] = f2bf(y - bf2f(h));
                }
            }
        }
}

// ---------------- x2 -> x2ht transpose (hi bf16 only) -----------------------
// Per block: 128 keys x 128 dims. x2ht[d][key] = f2bf(x2[key][d]).
__global__ __launch_bounds__(256) void prepVt_kernel(const float* __restrict__ src,
        unsigned short* __restrict__ x2ht) {
    __shared__ unsigned short T[128 * 136];
    const int d0 = blockIdx.x * 128, k0 = blockIdx.y * 128;
    const int t = threadIdx.x;
    const int cg = t & 31, rg = t >> 5;
#pragma unroll
    for (int i = 0; i < 16; ++i) {
        int row = i * 8 + rg;
        float4 v = *(const float4*)(src + (size_t)(k0 + row) * DM + d0 + cg * 4);
        float ff[4] = {v.x, v.y, v.z, v.w};
        int rsw = row ^ ((cg & 15) << 3);
#pragma unroll
        for (int j = 0; j < 4; ++j)
            T[(cg * 4 + j) * 136 + rsw] = f2bf(ff[j]);
    }
    __syncthreads();
#pragma unroll
    for (int ii = 0; ii < 8; ++ii) {
        int dl = ii * 16 + (t >> 4);
        int ko = (t & 15) * 8;
        u16x8 vv = *(const u16x8*)&T[dl * 136 + (ko ^ (((dl >> 2) & 15) << 3))];
        *(u16x8*)(x2ht + (size_t)(d0 + dl) * KEYS_TOTAL + k0 + ko) = vv;
    }
}

// ---------------- fused attention: per (chunk, batch), CHUNK=256 ------------
// QK double-buffered: buf s at s*40960 {Qh 4K | Ql 4K | Kf 32K fp32}.
// K staged as RAW fp32 x2; hi/lo bf16 split done in-register per fragment
// (identical f2bf math as the old splitT -> bit-identical numerics).
// PV aliases: Pb@0 (33792) | Vb[s]@33792+s*16384 | redb@66560 | mrow/lrow.
__global__ __launch_bounds__(512, 4) void attn_kernel(
        const unsigned short* __restrict__ Q2,    // [2048][1024] hi|lo (M)
        const float* __restrict__ x2f,            // [131072][512] fp32
        const unsigned short* __restrict__ Vt,    // [512][131072] (x2^T hi)
        float* __restrict__ Opart,                // [512][64][512]
        float* __restrict__ ML) {                 // [512][128] (m|l)
    __shared__ char smem_raw[81920];
    unsigned short* Pb = (unsigned short*)smem_raw;            // [64][264]
    float* redb = (float*)(smem_raw + 66560);                  // [8][64]
    float* mrow = (float*)(smem_raw + 68608);                  // [64]
    float* lrow = (float*)(smem_raw + 68864);                  // [64]

    const int c = blockIdx.x, b = blockIdx.y;
    const int t = threadIdx.x, w = t >> 6, l = t & 63;
    const int c16 = l & 15, q = l >> 4, q8 = q << 3;
    const int rB = l >> 2, cB = (l & 3) << 3;
    const int rF = l >> 3, cF = (l & 7) << 2;     // fp32 staging: 8 rows/gld16
    const size_t key0 = (size_t)b * LKV + (size_t)c * CHUNK;

    f32x4 acc[4][2];
#pragma unroll
    for (int i = 0; i < 4; ++i)
#pragma unroll
        for (int jj = 0; jj < 2; ++jj) acc[i][jj] = (f32x4){0.f,0.f,0.f,0.f};

    auto stageQK = [&](int s, int k0) {
        char* base = smem_raw + s * 40960;
        unsigned short* Qh = (unsigned short*)base;
        unsigned short* Ql = (unsigned short*)(base + 4096);
        float* Kf = (float*)(base + 8192);        // [256][32] fp32
        if (w < 4)
            gld16(Q2 + (size_t)(b * 64 + w * 16 + rB) * 1024 + k0 + cB, &Qh[(w * 16) * 32]);
        else
            gld16(Q2 + (size_t)(b * 64 + (w - 4) * 16 + rB) * 1024 + 512 + k0 + cB, &Ql[((w - 4) * 16) * 32]);
#pragma unroll
        for (int i = 0; i < 4; ++i) {
            int r = w * 32 + i * 8;
            gld16(x2f + (key0 + r + rF) * DM + k0 + cF, &Kf[r * 32]);
        }
    };

    // ---- QK: S[64 rows][256 keys], pipelined staging
    stageQK(0, 0);
    __syncthreads();
#pragma unroll 1
    for (int k0 = 0; k0 < DM; k0 += 32) {
        const int s = (k0 >> 5) & 1;
        if (k0 + 32 < DM) stageQK(s ^ 1, k0 + 32);
        const unsigned short* Qh = (const unsigned short*)(smem_raw + s * 40960);
        const unsigned short* Ql = Qh + 2048;
        const float* Kf = (const float*)(smem_raw + s * 40960 + 8192);
        bf16x8 ah[4], al[4];
#pragma unroll
        for (int mt = 0; mt < 4; ++mt) {
            ah[mt] = *(const bf16x8*)&Qh[(mt * 16 + c16) * 32 + q8];
            al[mt] = *(const bf16x8*)&Ql[(mt * 16 + c16) * 32 + q8];
        }
#pragma unroll
        for (int nt = 0; nt < 2; ++nt) {
            const float* kp = &Kf[(w * 32 + nt * 16 + c16) * 32 + q8];
            float4 f0 = *(const float4*)kp;
            float4 f1 = *(const float4*)(kp + 4);
            float ff[8] = {f0.x, f0.y, f0.z, f0.w, f1.x, f1.y, f1.z, f1.w};
            bf16x8 bh, bl;
#pragma unroll
            for (int i2 = 0; i2 < 8; ++i2) {
                unsigned short hb = f2bf(ff[i2]);
                bh[i2] = (short)hb;
                bl[i2] = (short)f2bf(ff[i2] - bf2f(hb));
            }
#pragma unroll
            for (int mt = 0; mt < 4; ++mt) {
                acc[mt][nt] = __builtin_amdgcn_mfma_f32_16x16x32_bf16(ah[mt], bh, acc[mt][nt], 0, 0, 0);
                acc[mt][nt] = __builtin_amdgcn_mfma_f32_16x16x32_bf16(al[mt], bh, acc[mt][nt], 0, 0, 0);
                acc[mt][nt] = __builtin_amdgcn_mfma_f32_16x16x32_bf16(ah[mt], bl, acc[mt][nt], 0, 0, 0);
            }
        }
        __syncthreads();
    }

    auto stagePV = [&](int s, int h, int ks) {
        unsigned short* Vb = (unsigned short*)(smem_raw + 33792 + s * 16384);
#pragma unroll
        for (int jj = 0; jj < 2; ++jj) {
            int dloc = w * 32 + jj * 16;
            gld16(Vt + (size_t)(h * 256 + dloc + rB) * KEYS_TOTAL + key0 + ks * 32 + cB,
                  &Vb[dloc * 32]);
        }
    };
    // first PV stage rides under the softmax reductions
    stagePV(0, 0, 0);

    // ---- softmax over the chunk
#pragma unroll
    for (int mt = 0; mt < 4; ++mt)
#pragma unroll
        for (int nt = 0; nt < 2; ++nt)
#pragma unroll
            for (int r = 0; r < 4; ++r) acc[mt][nt][r] *= SCALE;

    float rmax_[4][4];
#pragma unroll
    for (int mt = 0; mt < 4; ++mt)
#pragma unroll
        for (int r = 0; r < 4; ++r)
            rmax_[mt][r] = fmaxf(acc[mt][0][r], acc[mt][1][r]);
#pragma unroll
    for (int off = 1; off < 16; off <<= 1)
#pragma unroll
        for (int mt = 0; mt < 4; ++mt)
#pragma unroll
            for (int r = 0; r < 4; ++r)
                rmax_[mt][r] = fmaxf(rmax_[mt][r], __shfl_xor(rmax_[mt][r], off));
    if (c16 == 0) {
#pragma unroll
        for (int mt = 0; mt < 4; ++mt)
#pragma unroll
            for (int r = 0; r < 4; ++r) redb[w * 64 + mt * 16 + q * 4 + r] = rmax_[mt][r];
    }
    __syncthreads();
    if (t < 64) {
        float m = redb[t];
#pragma unroll
        for (int ww = 1; ww < 8; ++ww) m = fmaxf(m, redb[ww * 64 + t]);
        mrow[t] = m;
    }
    __syncthreads();

    float rsum_[4][4];
#pragma unroll
    for (int mt = 0; mt < 4; ++mt)
#pragma unroll
        for (int r = 0; r < 4; ++r) {
            float m = mrow[mt * 16 + q * 4 + r];
            float s = 0.f;
#pragma unroll
            for (int nt = 0; nt < 2; ++nt) {
                float e = __expf(acc[mt][nt][r] - m);
                acc[mt][nt][r] = e;
                s += e;
            }
            rsum_[mt][r] = s;
        }
#pragma unroll
    for (int off = 1; off < 16; off <<= 1)
#pragma unroll
        for (int mt = 0; mt < 4; ++mt)
#pragma unroll
            for (int r = 0; r < 4; ++r) rsum_[mt][r] += __shfl_xor(rsum_[mt][r], off);
    if (c16 == 0) {
#pragma unroll
        for (int mt = 0; mt < 4; ++mt)
#pragma unroll
            for (int r = 0; r < 4; ++r) redb[w * 64 + mt * 16 + q * 4 + r] = rsum_[mt][r];
    }
    __syncthreads();
    if (t < 64) {
        float s = redb[t];
#pragma unroll
        for (int ww = 1; ww < 8; ++ww) s += redb[ww * 64 + t];
        lrow[t] = s;
    }
    // P -> LDS (bf16 row-major [row][key], stride PBS)
#pragma unroll
    for (int mt = 0; mt < 4; ++mt)
#pragma unroll
        for (int nt = 0; nt < 2; ++nt)
#pragma unroll
            for (int r = 0; r < 4; ++r)
                Pb[(mt * 16 + q * 4 + r) * PBS + w * 32 + nt * 16 + c16] = f2bf(acc[mt][nt][r]);
    __syncthreads();

    // ---- PV: U[64][512] = P @ x2_chunk, pipelined staging, dim-halves
    f32x4 accO[4][4];
#pragma unroll
    for (int i = 0; i < 4; ++i)
#pragma unroll
        for (int jj = 0; jj < 4; ++jj) accO[i][jj] = (f32x4){0.f,0.f,0.f,0.f};

#pragma unroll 1
    for (int ks = 0; ks < 8; ++ks) {          // h = 0 (dims 0..255)
        const int s = ks & 1;
        if (ks < 7) stagePV(s ^ 1, 0, ks + 1);
        else        stagePV(s ^ 1, 1, 0);
        const unsigned short* Vb = (const unsigned short*)(smem_raw + 33792 + s * 16384);
        bf16x8 ap[4];
#pragma unroll
        for (int mt = 0; mt < 4; ++mt)
            ap[mt] = *(const bf16x8*)&Pb[(mt * 16 + c16) * PBS + ks * 32 + q8];
#pragma unroll
        for (int nt = 0; nt < 2; ++nt) {
            bf16x8 bvv = *(const bf16x8*)&Vb[(w * 32 + nt * 16 + c16) * 32 + q8];
#pragma unroll
            for (int mt = 0; mt < 4; ++mt)
                accO[mt][nt] = __builtin_amdgcn_mfma_f32_16x16x32_bf16(ap[mt], bvv, accO[mt][nt], 0, 0, 0);
        }
        __syncthreads();
    }
#pragma unroll 1
    for (int ks = 0; ks < 8; ++ks) {          // h = 1 (dims 256..511)
        const int s = ks & 1;
        if (ks < 7) stagePV(s ^ 1, 1, ks + 1);
        const unsigned short* Vb = (const unsigned short*)(smem_raw + 33792 + s * 16384);
        bf16x8 ap[4];
#pragma unroll
        for (int mt = 0; mt < 4; ++mt)
            ap[mt] = *(const bf16x8*)&Pb[(mt * 16 + c16) * PBS + ks * 32 + q8];
#pragma unroll
        for (int nt = 0; nt < 2; ++nt) {
            bf16x8 bvv = *(const bf16x8*)&Vb[(w * 32 + nt * 16 + c16) * 32 + q8];
#pragma unroll
            for (int mt = 0; mt < 4; ++mt)
                accO[mt][2 + nt] = __builtin_amdgcn_mfma_f32_16x16x32_bf16(ap[mt], bvv, accO[mt][2 + nt], 0, 0, 0);
        }
        __syncthreads();
    }

    const size_t part = (size_t)b * NCHUNK + c;
#pragma unroll
    for (int mt = 0; mt < 4; ++mt)
#pragma unroll
        for (int h = 0; h < 2; ++h)
#pragma unroll
            for (int nt = 0; nt < 2; ++nt) {
                int col = h * 256 + w * 32 + nt * 16 + c16;
#pragma unroll
                for (int r = 0; r < 4; ++r)
                    Opart[(part * 64 + mt * 16 + q * 4 + r) * 512 + col] = accO[mt][h * 2 + nt][r];
            }
    if (t < 64) {
        ML[part * 128 + t]      = mrow[t];
        ML[part * 128 + 64 + t] = lrow[t];
    }
}

// ---------------- combine chunk partials -> U (bf16 hi/lo) ------------------
__global__ __launch_bounds__(128) void combine_kernel(const float* __restrict__ Opart,
                                                      const float* __restrict__ ML,
                                                      unsigned short* __restrict__ Uh,
                                                      unsigned short* __restrict__ Ul) {
    const int b = blockIdx.x >> 6, row = blockIdx.x & 63;
    const int t = threadIdx.x;
    float m[NCHUNK], lv[NCHUNK];
    float M = -1e30f;
#pragma unroll
    for (int c = 0; c < NCHUNK; ++c) {
        m[c]  = ML[(size_t)(b * NCHUNK + c) * 128 + row];
        lv[c] = ML[(size_t)(b * NCHUNK + c) * 128 + 64 + row];
        M = fmaxf(M, m[c]);
    }
    float den = 0.f, wgt[NCHUNK];
#pragma unroll
    for (int c = 0; c < NCHUNK; ++c) { wgt[c] = __expf(m[c] - M); den += wgt[c] * lv[c]; }
    float4 o = make_float4(0.f, 0.f, 0.f, 0.f);
#pragma unroll
    for (int c = 0; c < NCHUNK; ++c) {
        float4 v = *(const float4*)&Opart[((size_t)(b * NCHUNK + c) * 64 + row) * 512 + t * 4];
        o.x += wgt[c] * v.x; o.y += wgt[c] * v.y; o.z += wgt[c] * v.z; o.w += wgt[c] * v.w;
    }
    const float inv = 1.f / den;
    float rr[4] = {o.x * inv, o.y * inv, o.z * inv, o.w * inv};
    u16x4 h, lo_;
#pragma unroll
    for (int j = 0; j < 4; ++j) {
        h[j]   = f2bf(rr[j]);
        lo_[j] = f2bf(rr[j] - bf2f(h[j]));
    }
    size_t base = ((size_t)(b * 64 + row)) * 512 + t * 4;
    *(u16x4*)&Uh[base] = h;
    *(u16x4*)&Ul[base] = lo_;
}

extern "C" void kernel_launch(void* const* d_in, const int* in_sizes, int n_in,
                              void* d_out, int out_size, void* d_ws, size_t ws_size,
                              hipStream_t stream) {
    const float* x1 = (const float*)d_in[0];   // [32,64,512]
    const float* x2 = (const float*)d_in[1];   // [32,4096,512]
    const float* wq = (const float*)d_in[3];
    const float* bq = (const float*)d_in[4];
    const float* wk = (const float*)d_in[5];
    // bk (d_in[6]) unused: per-row constant in scores, cancelled by softmax.
    const float* wv = (const float*)d_in[7];
    const float* bv = (const float*)d_in[8];
    float* out = (float*)d_out;

    char* ws = (char*)d_ws;
    unsigned short* x2ht  = (unsigned short*)(ws);               // 134,217,728 B
    float*          Opart = (float*)(ws + 134217728);            //  67,108,864 B
    float*          ML    = (float*)(ws + 201326592);            //     262,144 B
    unsigned short* M2    = (unsigned short*)(ws + 201588736);   //   4,194,304 B
    unsigned short* x1h   = (unsigned short*)(ws + 205783040);   //   2,097,152 B
    unsigned short* x1l   = (unsigned short*)(ws + 207880192);   //   2,097,152 B
    unsigned short* Uh    = (unsigned short*)(ws + 209977344);   //   2,097,152 B
    unsigned short* Ul    = (unsigned short*)(ws + 212074496);   //   2,097,152 B
    unsigned short* q1h   = (unsigned short*)(ws + 214171648);   //   2,097,152 B
    unsigned short* q1l   = (unsigned short*)(ws + 216268800);   //   2,097,152 B
    unsigned short* wqh   = (unsigned short*)(ws + 218365952);   //     524,288 B
    unsigned short* wql   = (unsigned short*)(ws + 218890240);
    unsigned short* wkth  = (unsigned short*)(ws + 219414528);
    unsigned short* wktl  = (unsigned short*)(ws + 219938816);
    unsigned short* wvh   = (unsigned short*)(ws + 220463104);
    unsigned short* wvl   = (unsigned short*)(ws + 220987392);   // end 221,511,680

    // --- x2 -> x2ht transpose (hi bf16), the only big preprocessing pass ---
    prepVt_kernel<<<dim3(4, 1024), 256, 0, stream>>>(x2, x2ht);

    // --- merged prep: split x1/wq/wv + transpose-split wk (one launch) ---
    prep_kernel<<<832, 256, 0, stream>>>(x1, wq, wk, wv,
                                         x1h, x1l, wqh, wql,
                                         wkth, wktl, wvh, wvl);

    // --- weight chain: q~ = x1 Wq^T + bq ; M = q~ @ Wk ---
    sgemm_kernel<<<dim3(4, 16), 256, 0, stream>>>(x1h, x1l, wqh, wql,
                                                  bq, 2, q1h, q1l, nullptr);
    sgemm_kernel<<<dim3(4, 16), 256, 0, stream>>>(q1h, q1l, wkth, wktl,
                                                  nullptr, 0, M2, nullptr, nullptr);

    // --- fused attention (S = M @ x2^T from raw fp32 x2, U = P @ x2) ---
    attn_kernel<<<dim3(NCHUNK, NB), 512, 0, stream>>>(M2, x2, x2ht, Opart, ML);
    combine_kernel<<<NB * LQ, 128, 0, stream>>>(Opart, ML, Uh, Ul);

    // --- out = U @ Wv^T + bv ---
    sgemm_kernel<<<dim3(4, 16), 256, 0, stream>>>(Uh, Ul, wvh, wvl,
                                                  bv, 1, nullptr, nullptr, out);
}